// Round 7
// baseline (13.740 us; speedup 1.0000x reference)
//
#include <hip/hip_runtime.h>
#include <cmath>

#define BATCH_N 8192

// ---------------------------------------------------------------------------
// Host-side setup: P, Pddot, A_eq are deterministic (built by _build_basis()
// with no randomness), so Q (6x30) is computed on the HOST in fp64:
//   cost = 10*(Pddot^T Pddot) + 10*(A^T A)   (11x11, SPD, from float32-cast basis)
//   M    = inv(-cost)
//   AM   = A @ M                              (6x11)
//   W    = I + 10 * (AM @ A^T)                (6x6, eigvals in [0,1))
//   S    = sum_{j=1..299} W^j
//   K    = -(10*S + 10*I) @ AM                (6x11)
//   Q    = K @ P^T                            (6x30)
// out_x = bx @ Q, out_y = by @ Q.
// Passed to the kernel TRANSPOSED + padded: qt[c][i] = Q[i][c], qt[c][6..7]=0.
// ---------------------------------------------------------------------------
struct alignas(16) QArg {
  float qt[30][8];
};

static void build_Q(QArg* Qa) {
  double t[30];
  const double step = 1.0 / 29.0;
  for (int i = 0; i < 30; ++i) t[i] = i * step;
  t[29] = 1.0;  // numpy linspace forces endpoint

  static const double c10[11] = {1, 10, 45, 120, 210, 252, 210, 120, 45, 10, 1};
  static const double c9[10] = {1, 9, 36, 84, 126, 126, 84, 36, 9, 1};
  static const double c8[9] = {1, 8, 28, 56, 70, 56, 28, 8, 1};

  double P64[30][11], B9[30][10], B8[30][9];
  for (int i = 0; i < 30; ++i) {
    for (int k = 0; k <= 10; ++k)
      P64[i][k] = c10[k] * std::pow(t[i], (double)k) * std::pow(1.0 - t[i], (double)(10 - k));
    for (int k = 0; k <= 9; ++k)
      B9[i][k] = c9[k] * std::pow(t[i], (double)k) * std::pow(1.0 - t[i], (double)(9 - k));
    for (int k = 0; k <= 8; ++k)
      B8[i][k] = c8[k] * std::pow(t[i], (double)k) * std::pow(1.0 - t[i], (double)(8 - k));
  }
  double Pdot64[30][11], Pddot64[30][11];
  for (int i = 0; i < 30; ++i)
    for (int j = 0; j < 11; ++j) {
      double a = (j >= 1 && j <= 10) ? B9[i][j - 1] : 0.0;
      double bb = (j <= 9) ? B9[i][j] : 0.0;
      Pdot64[i][j] = 10.0 * (a - bb);
      double p2 = (j >= 2) ? B8[i][j - 2] : 0.0;
      double p1 = (j >= 1 && j <= 9) ? B8[i][j - 1] : 0.0;
      double p0 = (j <= 8) ? B8[i][j] : 0.0;
      Pddot64[i][j] = 90.0 * (p2 - 2.0 * p1 + p0);
    }

  float Pf[30][11], Pdf[30][11];
  for (int i = 0; i < 30; ++i)
    for (int j = 0; j < 11; ++j) {
      Pf[i][j] = (float)P64[i][j];
      Pdf[i][j] = (float)Pddot64[i][j];
    }
  float Af[6][11];
  for (int j = 0; j < 11; ++j) {
    Af[0][j] = (float)P64[0][j];
    Af[1][j] = (float)Pdot64[0][j];
    Af[2][j] = (float)Pddot64[0][j];
    Af[3][j] = (float)P64[29][j];
    Af[4][j] = (float)Pdot64[29][j];
    Af[5][j] = (float)Pddot64[29][j];
  }

  double aug[11][22];
  for (int r = 0; r < 11; ++r)
    for (int c = 0; c < 11; ++c) {
      double s = 0.0;
      for (int k = 0; k < 30; ++k) s += (double)Pdf[k][r] * (double)Pdf[k][c];
      double s2 = 0.0;
      for (int k = 0; k < 6; ++k) s2 += (double)Af[k][r] * (double)Af[k][c];
      aug[r][c] = 10.0 * s + 10.0 * s2;
      aug[r][11 + c] = (r == c) ? 1.0 : 0.0;
    }
  for (int p = 0; p < 11; ++p) {
    double piv = aug[p][p];
    for (int c = 0; c < 22; ++c) aug[p][c] /= piv;
    for (int r = 0; r < 11; ++r) {
      if (r == p) continue;
      double f = aug[r][p];
      for (int c = 0; c < 22; ++c) aug[r][c] -= f * aug[p][c];
    }
  }

  double AM[6][11];
  for (int r = 0; r < 6; ++r)
    for (int c = 0; c < 11; ++c) {
      double s = 0.0;
      for (int k = 0; k < 11; ++k) s += (double)Af[r][k] * aug[k][11 + c];
      AM[r][c] = -s;
    }
  double W[6][6];
  for (int i = 0; i < 6; ++i)
    for (int j = 0; j < 6; ++j) {
      double s = 0.0;
      for (int k = 0; k < 11; ++k) s += AM[i][k] * (double)Af[j][k];
      W[i][j] = ((i == j) ? 1.0 : 0.0) + 10.0 * s;
    }
  double S[6][6] = {}, Pw[6][6] = {};
  for (int i = 0; i < 6; ++i) Pw[i][i] = 1.0;
  for (int it = 0; it < 299; ++it) {
    double T[6][6];
    for (int i = 0; i < 6; ++i)
      for (int j = 0; j < 6; ++j) {
        double s = 0.0;
        for (int k = 0; k < 6; ++k) s += Pw[i][k] * W[k][j];
        T[i][j] = s;
      }
    for (int i = 0; i < 6; ++i)
      for (int j = 0; j < 6; ++j) {
        Pw[i][j] = T[i][j];
        S[i][j] += T[i][j];
      }
  }
  double K[6][11];
  for (int i = 0; i < 6; ++i)
    for (int j = 0; j < 11; ++j) {
      double s = 0.0;
      for (int k = 0; k < 6; ++k)
        s += (S[i][k] + ((i == k) ? 1.0 : 0.0)) * AM[k][j];
      K[i][j] = -10.0 * s;
    }
  for (int i = 0; i < 6; ++i)
    for (int c = 0; c < 30; ++c) {
      double s = 0.0;
      for (int j = 0; j < 11; ++j) s += K[i][j] * (double)Pf[c][j];
      Qa->qt[c][i] = (float)s;  // transposed
    }
  for (int c = 0; c < 30; ++c) {
    Qa->qt[c][6] = 0.0f;
    Qa->qt[c][7] = 0.0f;
  }
}

// ---------------------------------------------------------------------------
// Cross-lane sum helpers. Pairing-permutation reduce (valid for sums):
//   quad_perm xor1 (0xB1), quad_perm xor2 (0x4E)  -> sum of each quad
//   row_half_mirror (0x141)                        -> sum of 8
//   row_mirror (0x140)                             -> sum of 16
//   ds_swizzle xor16 (0x401F)                      -> sum of 32
// DPP ops run at VALU speed (vs ds_bpermute on the LDS pipe).
// DPP ctrl must be a compile-time constant -> template parameter.
// ---------------------------------------------------------------------------
template <int CTRL>
__device__ __forceinline__ float dpp_add(float v) {
  int s = __builtin_amdgcn_update_dpp(0, __float_as_int(v), CTRL, 0xf, 0xf,
                                      false);
  return v + __int_as_float(s);
}
__device__ __forceinline__ float swz16_add(float v) {
  int s = __builtin_amdgcn_ds_swizzle(__float_as_int(v), 0x401F);
  return v + __int_as_float(s);
}

// ---------------------------------------------------------------------------
// Device kernel: W1 register-resident.
// 256-thread blocks (4 waves). Lane slot ul = t&31 owns hidden units
// 2*ul, 2*ul+1 (W1 rows in 88 VGPRs, loaded ONCE). Each 32-lane half runs
// one row-stream; 2 rows per stream (row = stream, stream + 4096).
// Per row: 11 broadcast float4 x-loads, 88 FMA, DPP+swizzle allreduce,
// masked-b assembly, 2 output columns per lane (float2 store, coalesced).
// 512 blocks -> 2048 waves -> 8 waves/CU.
// ---------------------------------------------------------------------------
__global__ __launch_bounds__(256) void traj_main(
    const float* __restrict__ x, const float* __restrict__ b,
    const float* __restrict__ W1, const float* __restrict__ b1,
    const float* __restrict__ W2, const float* __restrict__ b2, QArg Q,
    float* __restrict__ out) {
  const int t = threadIdx.x;      // 0..255
  const int ul = t & 31;          // unit slot: hidden units 2*ul, 2*ul+1
  const int wave = t >> 6;        // 0..3
  const int half = (t >> 5) & 1;  // row-stream within wave
  const int stream = (blockIdx.x * 4 + wave) * 2 + half;  // 0..4095

  // ---- one-time: this lane's two W1 rows -> registers ----
  float w0[44], w1[44];
  const float4* wp0 = (const float4*)(W1 + (2 * ul) * 44);
  const float4* wp1 = (const float4*)(W1 + (2 * ul + 1) * 44);
#pragma unroll
  for (int i = 0; i < 11; ++i) {
    float4 a = wp0[i];
    w0[4 * i + 0] = a.x; w0[4 * i + 1] = a.y;
    w0[4 * i + 2] = a.z; w0[4 * i + 3] = a.w;
    float4 c = wp1[i];
    w1[4 * i + 0] = c.x; w1[4 * i + 1] = c.y;
    w1[4 * i + 2] = c.z; w1[4 * i + 3] = c.w;
  }
  float2 w2a = *(const float2*)(W2 + 3 * 64 + 2 * ul);  // 8B aligned
  float2 w2b = *(const float2*)(W2 + 9 * 64 + 2 * ul);
  float2 b1v = *(const float2*)(b1 + 2 * ul);
  const float b23 = b2[3], b29 = b2[9];

  // this lane's two output columns (for ul < 30): c0, c0+1 (same x/y half)
  const int c0 = 2 * ul;
  const int cq = (c0 < 30) ? c0 : c0 - 30;
  float4 q0a, q0b, q1a, q1b;
  {
    const float* qc = &Q.qt[cq][0];  // 32B per column, 16B aligned
    q0a = *(const float4*)(qc + 0);
    q0b = *(const float4*)(qc + 4);
    q1a = *(const float4*)(qc + 8);
    q1b = *(const float4*)(qc + 12);
  }

#pragma unroll
  for (int r = 0; r < 2; ++r) {
    const int row = stream + r * 4096;

    // x row: broadcast within the 32-lane half
    const float4* xp = (const float4*)(x + row * 44);
    float a0 = b1v.x, a1 = b1v.y;
#pragma unroll
    for (int i = 0; i < 11; ++i) {
      float4 xv = xp[i];
      a0 += w0[4 * i + 0] * xv.x + w0[4 * i + 1] * xv.y +
            w0[4 * i + 2] * xv.z + w0[4 * i + 3] * xv.w;
      a1 += w1[4 * i + 0] * xv.x + w1[4 * i + 1] * xv.y +
            w1[4 * i + 2] * xv.z + w1[4 * i + 3] * xv.w;
    }
    float h0 = fmaxf(a0, 0.0f), h1 = fmaxf(a1, 0.0f);
    float hp3 = h0 * w2a.x + h1 * w2a.y;
    float hp9 = h0 * w2b.x + h1 * w2b.y;

    // allreduce across the 32 lanes of this half: 4 DPP + 1 ds_swizzle
    hp3 = dpp_add<0xB1>(hp3);   hp9 = dpp_add<0xB1>(hp9);    // quad xor1
    hp3 = dpp_add<0x4E>(hp3);   hp9 = dpp_add<0x4E>(hp9);    // quad xor2
    hp3 = dpp_add<0x141>(hp3);  hp9 = dpp_add<0x141>(hp9);   // half_mirror
    hp3 = dpp_add<0x140>(hp3);  hp9 = dpp_add<0x140>(hp9);   // row_mirror
    hp3 = swz16_add(hp3);       hp9 = swz16_add(hp9);        // xor16
    const float bp3 = hp3 + b23;
    const float bp9 = hp9 + b29;

    // b row (broadcast within half)
    const float4* bpr = (const float4*)(b + row * 12);
    float4 bv0 = bpr[0], bv1 = bpr[1], bv2 = bpr[2];

    if (ul < 30) {
      const bool isx = (c0 < 30);
      const float s0 = isx ? bv0.x : bv1.z;
      const float s1 = isx ? bv0.y : bv1.w;
      const float s2 = isx ? bv0.z : bv2.x;
      const float s3 = isx ? bp3 : bp9;
      const float s4 = isx ? bv1.x : bv2.z;
      const float s5 = isx ? bv1.y : bv2.w;

      const float o0 = s0 * q0a.x + s1 * q0a.y + s2 * q0a.z + s3 * q0a.w +
                       s4 * q0b.x + s5 * q0b.y;
      const float o1 = s0 * q1a.x + s1 * q1a.y + s2 * q1a.z + s3 * q1a.w +
                       s4 * q1b.x + s5 * q1b.y;
      // byte offset 240*row + 8*ul -> 8B aligned; coalesced across lanes
      *(float2*)(out + row * 60 + c0) = make_float2(o0, o1);
    }
  }
}

extern "C" void kernel_launch(void* const* d_in, const int* in_sizes, int n_in,
                              void* d_out, int out_size, void* d_ws,
                              size_t ws_size, hipStream_t stream) {
  const float* x = (const float*)d_in[0];   // (8192, 44)
  const float* b = (const float*)d_in[1];   // (8192, 12)
  const float* W1 = (const float*)d_in[2];  // (64, 44)
  const float* b1 = (const float*)d_in[3];  // (64,)
  const float* W2 = (const float*)d_in[4];  // (12, 64)
  const float* b2 = (const float*)d_in[5];  // (12,)
  float* out = (float*)d_out;               // (8192, 60)

  QArg Qa;
  build_Q(&Qa);  // pure host fp64 math, deterministic, graph-capture safe

  traj_main<<<BATCH_N / 16, 256, 0, stream>>>(x, b, W1, b1, W2, b2, Qa, out);
}

// Round 8
// 12.004 us; speedup vs baseline: 1.1446x; 1.1446x over previous
//
#include <hip/hip_runtime.h>
#include <cmath>

#define BATCH_N 8192

// ---------------------------------------------------------------------------
// Host-side setup: P, Pddot, A_eq are deterministic (built by _build_basis()
// with no randomness), so Q (6x30) is computed on the HOST in fp64:
//   cost = 10*(Pddot^T Pddot) + 10*(A^T A)   (11x11, SPD, from float32-cast basis)
//   M    = inv(-cost)
//   AM   = A @ M                              (6x11)
//   W    = I + 10 * (AM @ A^T)                (6x6, eigvals in [0,1))
//   S    = sum_{j=1..299} W^j
//   K    = -(10*S + 10*I) @ AM                (6x11)
//   Q    = K @ P^T                            (6x30)
// out_x = bx @ Q, out_y = by @ Q.
// Passed to the kernel TRANSPOSED + padded: qt[c][i] = Q[i][c], qt[c][6..7]=0,
// so a lane's two output columns are 4 aligned float4 kernarg loads.
// ---------------------------------------------------------------------------
struct alignas(16) QArg {
  float qt[30][8];
};

static void build_Q(QArg* Qa) {
  double t[30];
  const double step = 1.0 / 29.0;
  for (int i = 0; i < 30; ++i) t[i] = i * step;
  t[29] = 1.0;  // numpy linspace forces endpoint

  static const double c10[11] = {1, 10, 45, 120, 210, 252, 210, 120, 45, 10, 1};
  static const double c9[10] = {1, 9, 36, 84, 126, 126, 84, 36, 9, 1};
  static const double c8[9] = {1, 8, 28, 56, 70, 56, 28, 8, 1};

  double P64[30][11], B9[30][10], B8[30][9];
  for (int i = 0; i < 30; ++i) {
    for (int k = 0; k <= 10; ++k)
      P64[i][k] = c10[k] * std::pow(t[i], (double)k) * std::pow(1.0 - t[i], (double)(10 - k));
    for (int k = 0; k <= 9; ++k)
      B9[i][k] = c9[k] * std::pow(t[i], (double)k) * std::pow(1.0 - t[i], (double)(9 - k));
    for (int k = 0; k <= 8; ++k)
      B8[i][k] = c8[k] * std::pow(t[i], (double)k) * std::pow(1.0 - t[i], (double)(8 - k));
  }
  double Pdot64[30][11], Pddot64[30][11];
  for (int i = 0; i < 30; ++i)
    for (int j = 0; j < 11; ++j) {
      double a = (j >= 1 && j <= 10) ? B9[i][j - 1] : 0.0;
      double bb = (j <= 9) ? B9[i][j] : 0.0;
      Pdot64[i][j] = 10.0 * (a - bb);
      double p2 = (j >= 2) ? B8[i][j - 2] : 0.0;
      double p1 = (j >= 1 && j <= 9) ? B8[i][j - 1] : 0.0;
      double p0 = (j <= 8) ? B8[i][j] : 0.0;
      Pddot64[i][j] = 90.0 * (p2 - 2.0 * p1 + p0);
    }

  float Pf[30][11], Pdf[30][11];
  for (int i = 0; i < 30; ++i)
    for (int j = 0; j < 11; ++j) {
      Pf[i][j] = (float)P64[i][j];
      Pdf[i][j] = (float)Pddot64[i][j];
    }
  float Af[6][11];
  for (int j = 0; j < 11; ++j) {
    Af[0][j] = (float)P64[0][j];
    Af[1][j] = (float)Pdot64[0][j];
    Af[2][j] = (float)Pddot64[0][j];
    Af[3][j] = (float)P64[29][j];
    Af[4][j] = (float)Pdot64[29][j];
    Af[5][j] = (float)Pddot64[29][j];
  }

  double aug[11][22];
  for (int r = 0; r < 11; ++r)
    for (int c = 0; c < 11; ++c) {
      double s = 0.0;
      for (int k = 0; k < 30; ++k) s += (double)Pdf[k][r] * (double)Pdf[k][c];
      double s2 = 0.0;
      for (int k = 0; k < 6; ++k) s2 += (double)Af[k][r] * (double)Af[k][c];
      aug[r][c] = 10.0 * s + 10.0 * s2;
      aug[r][11 + c] = (r == c) ? 1.0 : 0.0;
    }
  for (int p = 0; p < 11; ++p) {
    double piv = aug[p][p];
    for (int c = 0; c < 22; ++c) aug[p][c] /= piv;
    for (int r = 0; r < 11; ++r) {
      if (r == p) continue;
      double f = aug[r][p];
      for (int c = 0; c < 22; ++c) aug[r][c] -= f * aug[p][c];
    }
  }

  double AM[6][11];
  for (int r = 0; r < 6; ++r)
    for (int c = 0; c < 11; ++c) {
      double s = 0.0;
      for (int k = 0; k < 11; ++k) s += (double)Af[r][k] * aug[k][11 + c];
      AM[r][c] = -s;
    }
  double W[6][6];
  for (int i = 0; i < 6; ++i)
    for (int j = 0; j < 6; ++j) {
      double s = 0.0;
      for (int k = 0; k < 11; ++k) s += AM[i][k] * (double)Af[j][k];
      W[i][j] = ((i == j) ? 1.0 : 0.0) + 10.0 * s;
    }
  double S[6][6] = {}, Pw[6][6] = {};
  for (int i = 0; i < 6; ++i) Pw[i][i] = 1.0;
  for (int it = 0; it < 299; ++it) {
    double T[6][6];
    for (int i = 0; i < 6; ++i)
      for (int j = 0; j < 6; ++j) {
        double s = 0.0;
        for (int k = 0; k < 6; ++k) s += Pw[i][k] * W[k][j];
        T[i][j] = s;
      }
    for (int i = 0; i < 6; ++i)
      for (int j = 0; j < 6; ++j) {
        Pw[i][j] = T[i][j];
        S[i][j] += T[i][j];
      }
  }
  double K[6][11];
  for (int i = 0; i < 6; ++i)
    for (int j = 0; j < 11; ++j) {
      double s = 0.0;
      for (int k = 0; k < 6; ++k)
        s += (S[i][k] + ((i == k) ? 1.0 : 0.0)) * AM[k][j];
      K[i][j] = -10.0 * s;
    }
  for (int i = 0; i < 6; ++i)
    for (int c = 0; c < 30; ++c) {
      double s = 0.0;
      for (int j = 0; j < 11; ++j) s += K[i][j] * (double)Pf[c][j];
      Qa->qt[c][i] = (float)s;  // transposed
    }
  for (int c = 0; c < 30; ++c) {
    Qa->qt[c][6] = 0.0f;
    Qa->qt[c][7] = 0.0f;
  }
}

// ---------------------------------------------------------------------------
// Device kernel: W1 register-resident.
// 256-thread blocks (4 waves). Lane slot ul = t&31 owns hidden units
// 2*ul, 2*ul+1 (W1 rows held in 88 VGPRs, loaded ONCE). Each 32-lane half
// runs one row-stream; 2 rows per stream (row = stream, stream + 4096).
// Per row: 11 broadcast float4 x-loads, 88 FMA, 5-step butterfly reduce,
// masked-b assembly, 2 output columns per lane (float2 store, coalesced).
// 512 blocks -> 2048 waves -> 8 waves/CU.
// (Round-5 configuration — best measured at 11.98 us; DPP variant of the
// reduce regressed in round 7, reverted.)
// ---------------------------------------------------------------------------
__global__ __launch_bounds__(256) void traj_main(
    const float* __restrict__ x, const float* __restrict__ b,
    const float* __restrict__ W1, const float* __restrict__ b1,
    const float* __restrict__ W2, const float* __restrict__ b2, QArg Q,
    float* __restrict__ out) {
  const int t = threadIdx.x;      // 0..255
  const int ul = t & 31;          // unit slot: hidden units 2*ul, 2*ul+1
  const int wave = t >> 6;        // 0..3
  const int half = (t >> 5) & 1;  // row-stream within wave
  const int stream = (blockIdx.x * 4 + wave) * 2 + half;  // 0..4095

  // ---- one-time: this lane's two W1 rows -> registers ----
  float w0[44], w1[44];
  const float4* wp0 = (const float4*)(W1 + (2 * ul) * 44);
  const float4* wp1 = (const float4*)(W1 + (2 * ul + 1) * 44);
#pragma unroll
  for (int i = 0; i < 11; ++i) {
    float4 a = wp0[i];
    w0[4 * i + 0] = a.x; w0[4 * i + 1] = a.y;
    w0[4 * i + 2] = a.z; w0[4 * i + 3] = a.w;
    float4 c = wp1[i];
    w1[4 * i + 0] = c.x; w1[4 * i + 1] = c.y;
    w1[4 * i + 2] = c.z; w1[4 * i + 3] = c.w;
  }
  float2 w2a = *(const float2*)(W2 + 3 * 64 + 2 * ul);  // 8B aligned
  float2 w2b = *(const float2*)(W2 + 9 * 64 + 2 * ul);
  float2 b1v = *(const float2*)(b1 + 2 * ul);
  const float b23 = b2[3], b29 = b2[9];

  // this lane's two output columns (for ul < 30): c0, c0+1 (same x/y half)
  const int c0 = 2 * ul;
  const int cq = (c0 < 30) ? c0 : c0 - 30;
  float4 q0a, q0b, q1a, q1b;
  {
    const float* qc = &Q.qt[cq][0];  // 32B per column, 16B aligned
    q0a = *(const float4*)(qc + 0);
    q0b = *(const float4*)(qc + 4);
    q1a = *(const float4*)(qc + 8);
    q1b = *(const float4*)(qc + 12);
  }

#pragma unroll
  for (int r = 0; r < 2; ++r) {
    const int row = stream + r * 4096;

    // x row: broadcast within the 32-lane half
    const float4* xp = (const float4*)(x + row * 44);
    float a0 = b1v.x, a1 = b1v.y;
#pragma unroll
    for (int i = 0; i < 11; ++i) {
      float4 xv = xp[i];
      a0 += w0[4 * i + 0] * xv.x + w0[4 * i + 1] * xv.y +
            w0[4 * i + 2] * xv.z + w0[4 * i + 3] * xv.w;
      a1 += w1[4 * i + 0] * xv.x + w1[4 * i + 1] * xv.y +
            w1[4 * i + 2] * xv.z + w1[4 * i + 3] * xv.w;
    }
    float h0 = fmaxf(a0, 0.0f), h1 = fmaxf(a1, 0.0f);
    float hp3 = h0 * w2a.x + h1 * w2a.y;
    float hp9 = h0 * w2b.x + h1 * w2b.y;

    // butterfly reduce across the 32 lanes of this half (stays within half)
#pragma unroll
    for (int m = 1; m < 32; m <<= 1) {
      hp3 += __shfl_xor(hp3, m, 64);
      hp9 += __shfl_xor(hp9, m, 64);
    }
    const float bp3 = hp3 + b23;
    const float bp9 = hp9 + b29;

    // b row (broadcast within half)
    const float4* bpr = (const float4*)(b + row * 12);
    float4 bv0 = bpr[0], bv1 = bpr[1], bv2 = bpr[2];

    if (ul < 30) {
      // select x-coeffs or y-coeffs per lane (branchless, constant indices)
      const bool isx = (c0 < 30);
      const float s0 = isx ? bv0.x : bv1.z;
      const float s1 = isx ? bv0.y : bv1.w;
      const float s2 = isx ? bv0.z : bv2.x;
      const float s3 = isx ? bp3 : bp9;
      const float s4 = isx ? bv1.x : bv2.z;
      const float s5 = isx ? bv1.y : bv2.w;

      const float o0 = s0 * q0a.x + s1 * q0a.y + s2 * q0a.z + s3 * q0a.w +
                       s4 * q0b.x + s5 * q0b.y;
      const float o1 = s0 * q1a.x + s1 * q1a.y + s2 * q1a.z + s3 * q1a.w +
                       s4 * q1b.x + s5 * q1b.y;
      // byte offset 240*row + 8*ul -> 8B aligned; coalesced across lanes
      *(float2*)(out + row * 60 + c0) = make_float2(o0, o1);
    }
  }
}

extern "C" void kernel_launch(void* const* d_in, const int* in_sizes, int n_in,
                              void* d_out, int out_size, void* d_ws,
                              size_t ws_size, hipStream_t stream) {
  const float* x = (const float*)d_in[0];   // (8192, 44)
  const float* b = (const float*)d_in[1];   // (8192, 12)
  const float* W1 = (const float*)d_in[2];  // (64, 44)
  const float* b1 = (const float*)d_in[3];  // (64,)
  const float* W2 = (const float*)d_in[4];  // (12, 64)
  const float* b2 = (const float*)d_in[5];  // (12,)
  float* out = (float*)d_out;               // (8192, 60)

  QArg Qa;
  build_Q(&Qa);  // pure host fp64 math, deterministic, graph-capture safe

  traj_main<<<BATCH_N / 16, 256, 0, stream>>>(x, b, W1, b1, W2, b2, Qa, out);
}